// Round 13
// baseline (187.614 us; speedup 1.0000x reference)
//
#include <hip/hip_runtime.h>
#include <hip/hip_bf16.h>

#define DH 1024      // hidden dim
#define NE 8         // experts
#define NT 8192      // tokens (4*2048)
#define NTK 16384    // tokens * top-k
#define BM 128
#define BN 256
#define NSUB 32      // K sub-tiles of 32

typedef __bf16 bf16x8 __attribute__((ext_vector_type(8)));
typedef float f32x4 __attribute__((ext_vector_type(4)));
typedef unsigned short u16;
typedef u16 u16x8 __attribute__((ext_vector_type(8)));
typedef u16 u16x4 __attribute__((ext_vector_type(4)));

__device__ __forceinline__ u16 f2bf(float f) {
  union { float f; unsigned u; } v; v.f = f;
  return (u16)((v.u + 0x7fffu + ((v.u >> 16) & 1u)) >> 16);  // RNE
}
__device__ __forceinline__ float bf2f(u16 h) {
  union { unsigned u; float f; } v; v.u = ((unsigned)h) << 16;
  return v.f;
}
__device__ __forceinline__ float gelu_tanh(float v) {
  float y = 0.7978845608028654f * (v + 0.044715f * v * v * v);
  float t = 1.f - 2.f / (1.f + __expf(2.f * y));   // tanh(y)
  return 0.5f * v * (1.f + t);
}

// async global->LDS, 16B per lane; lane l lands at ldsbase + l*16B.
__device__ __forceinline__ void gload_lds16(const u16* g, u16* l) {
  __builtin_amdgcn_global_load_lds(
      (const __attribute__((address_space(1))) void*)g,
      (__attribute__((address_space(3))) void*)l, 16, 0, 0);
}

// ---- fused pre-pass: blocks 0..4095 transpose+convert weights,
//      blocks 4096..4351 run the router (+ x->bf16 convert).
//      BW-bound transpose hides the compute-bound router.
__global__ __launch_bounds__(256) void prep_kernel(
    const float* __restrict__ w1, const float* __restrict__ w2,
    const float* __restrict__ x, const float* __restrict__ wr,
    u16* __restrict__ w1t, u16* __restrict__ w2t,
    float* __restrict__ logits_out, int* __restrict__ tkidx,
    float* __restrict__ tkp, int* __restrict__ counts,
    u16* __restrict__ xb) {
  __shared__ __attribute__((aligned(16))) char smem[33088];
  int bid = blockIdx.x;
  int tid = threadIdx.x;

  if (bid < 4096) {
    // ---- transpose role: w[e][d][n] (f32) -> wt[e][n][d] (bf16)
    float (*tile)[65] = (float(*)[65])smem;    // 64x65 f32 = 16.6KB
    int z = bid >> 8;                          // 0..15
    int rem = bid & 255;
    const float* src = (z < NE) ? (w1 + (size_t)z * DH * DH)
                                : (w2 + (size_t)(z - NE) * DH * DH);
    u16* dst = (z < NE) ? (w1t + (size_t)z * DH * DH)
                        : (w2t + (size_t)(z - NE) * DH * DH);
    int d0 = (rem >> 4) * 64, n0 = (rem & 15) * 64;
    int r16 = tid >> 4;       // 0..15
    int c4 = (tid & 15) * 4;  // 0..60
#pragma unroll
    for (int it = 0; it < 4; ++it) {
      int rr = it * 16 + r16;
      float4 v = *(const float4*)&src[(size_t)(d0 + rr) * DH + n0 + c4];
      tile[rr][c4] = v.x; tile[rr][c4 + 1] = v.y;
      tile[rr][c4 + 2] = v.z; tile[rr][c4 + 3] = v.w;
    }
    __syncthreads();
#pragma unroll
    for (int it = 0; it < 4; ++it) {
      int n = it * 16 + r16;
      u16x4 o;
      o[0] = f2bf(tile[c4][n]);     o[1] = f2bf(tile[c4 + 1][n]);
      o[2] = f2bf(tile[c4 + 2][n]); o[3] = f2bf(tile[c4 + 3][n]);
      *(u16x4*)&dst[(size_t)(n0 + n) * DH + d0 + c4] = o;
    }
    return;
  }

  // ---- router role: 32 tokens/block (8 per wave), fp32, LDS-staged wr^T.
  float (*wsh)[DH + 8] = (float(*)[DH + 8])smem;           // 8x1032 f32
  int* hist = (int*)(smem + NE * (DH + 8) * sizeof(float)); // 8 ints
  int rb = bid - 4096;  // 0..255
  for (int i = tid; i < DH * NE; i += 256) {
    int d = i >> 3, e = i & 7;
    wsh[e][d] = wr[i];
  }
  if (tid < NE) hist[tid] = 0;
  __syncthreads();

  int lane = tid & 63;
  int wv = tid >> 6;
  int t0 = rb * 32 + wv * 8;
#pragma unroll 1
  for (int i = 0; i < 8; ++i) {
    int t = t0 + i;
    const float4* xp = (const float4*)(x + (size_t)t * DH);
    u16* xbrow = xb + (size_t)t * DH;
    float a[8] = {0.f, 0.f, 0.f, 0.f, 0.f, 0.f, 0.f, 0.f};
#pragma unroll
    for (int it = 0; it < 4; ++it) {
      float4 xv = xp[it * 64 + lane];
      int d0 = (it * 64 + lane) * 4;
      u16x4 c4;
      c4[0] = f2bf(xv.x); c4[1] = f2bf(xv.y); c4[2] = f2bf(xv.z); c4[3] = f2bf(xv.w);
      *(u16x4*)(xbrow + d0) = c4;
#pragma unroll
      for (int e = 0; e < 8; ++e) {
        float4 w4 = *(const float4*)&wsh[e][d0];
        a[e] += xv.x * w4.x + xv.y * w4.y + xv.z * w4.z + xv.w * w4.w;
      }
    }
#pragma unroll
    for (int off = 32; off; off >>= 1) {
#pragma unroll
      for (int e = 0; e < 8; ++e) a[e] += __shfl_xor(a[e], off, 64);
    }
    if (lane < 8) logits_out[(size_t)t * NE + lane] = a[lane];
    if (lane == 0) {
      float m1 = a[0]; int i1 = 0;
#pragma unroll
      for (int e = 1; e < 8; ++e) if (a[e] > m1) { m1 = a[e]; i1 = e; }
      float m2 = -3.4e38f; int i2 = 0;
#pragma unroll
      for (int e = 0; e < 8; ++e) if (e != i1 && a[e] > m2) { m2 = a[e]; i2 = e; }
      float den = 0.f;
#pragma unroll
      for (int e = 0; e < 8; ++e) den += expf(a[e] - m1);
      tkidx[2 * t] = i1; tkidx[2 * t + 1] = i2;
      tkp[2 * t] = 1.0f / den;
      tkp[2 * t + 1] = expf(m2 - m1) / den;
      atomicAdd(&hist[i1], 1);
      atomicAdd(&hist[i2], 1);
    }
  }
  __syncthreads();
  if (tid < NE) atomicAdd(&counts[tid], hist[tid]);
}

// ---- scatter: block-hierarchical ranks; 8 global atomics per block.
//      Computes the expert-offset prefix locally (no offsets kernel).
__global__ __launch_bounds__(1024) void scatter_kernel(
    const int* __restrict__ tkidx, const float* __restrict__ tkp,
    const int* __restrict__ counts, int* __restrict__ cur,
    int* __restrict__ rows, int* __restrict__ posof, float* __restrict__ pp) {
  __shared__ int h[NE];
  __shared__ int base[NE];
  __shared__ int offsL[NE];
  int tid = threadIdx.x;
  int gid = blockIdx.x * 1024 + tid;  // < NTK
  if (tid < NE) h[tid] = 0;
  if (tid == 0) {
    int s = 0;
    for (int e = 0; e < NE; ++e) { offsL[e] = s; s += counts[e]; }
  }
  __syncthreads();
  int e = tkidx[gid];
  int myrank = atomicAdd(&h[e], 1);
  __syncthreads();
  if (tid < NE) base[tid] = atomicAdd(&cur[tid], h[tid]);
  __syncthreads();
  int pos = offsL[e] + base[e] + myrank;
  rows[pos] = gid >> 1;
  posof[gid] = pos;
  pp[pos] = tkp[gid];
}

// ---- grouped GEMM (r12 champion, unchanged):
//      128x256 tile, ring of 3 BK=32 sub-tile buffers (72KB, 2 blk/CU),
//      counted vmcnt(6)/3/0 (T3+T4), chunk-XOR swizzle both-sides (T2,
//      0-conflict verified), setprio MFMA (T5). blockIdx.x = expert:
//      round-robin id%8 pins expert e's 2MB weights into XCD e's L2.
// GELU=1: A = xb gathered via rows[]; out = gelu(A@W + b)   -> hbuf
// GELU=0: A = hbuf direct;           out = A@W + b          -> eo
template <int GELU>
__global__ __launch_bounds__(512, 4) void gemm_kernel(
    const u16* __restrict__ A, const u16* __restrict__ W,
    const float* __restrict__ bias, const int* __restrict__ counts,
    const int* __restrict__ rows, u16* __restrict__ outb) {
  int e = blockIdx.x;               // expert == XCD (id % 8 round-robin)
  int q = blockIdx.y;               // tile index within expert, n-fastest
  int cnt = counts[e];
  int nm = (cnt + BM - 1) / BM;
  if (q >= nm * 4) return;          // block-uniform, before any barrier
  int m0 = (q >> 2) * BM;
  int n0 = (q & 3) * BN;
  int seg = 0;
  for (int i = 0; i < e; ++i) seg += counts[i];   // uniform prefix

  // ring slot: A[128][32] (8KB) at 0, B[256][32] (16KB) at elem 4096
  __shared__ __attribute__((aligned(16))) u16 lds[3][12288];

  int tid = threadIdx.x;
  int lane = tid & 63;
  int wv = tid >> 6;            // 0..7

  // ---- staging: thread covers row tid>>2, chunk tid&3 (16B chunks of 64B
  // rows). Global chunk pre-swizzled: stored pos = c ^ ((row>>1)&3); same
  // XOR applied to source (involution, rule #21). ((128+r)>>1)&3 ==
  // ((r>>1)&3), so one swizzled offset serves A and both B halves.
  int srow = tid >> 2;                               // 0..127
  int sc8 = ((tid & 3) ^ ((srow >> 1) & 3)) * 8;     // elems
  int gi = m0 + srow;
  int cl = gi < cnt ? gi : cnt - 1;
  int arow = GELU ? rows[seg + cl] : (seg + cl);
  const u16* aSrc = A + (size_t)arow * DH + sc8;
  const u16* bSrc0 = W + (size_t)e * DH * DH + (size_t)(n0 + srow) * DH + sc8;
  const u16* bSrc1 = bSrc0 + (size_t)128 * DH;

  // per-wave-uniform LDS bases (gload writes lane l at base + l*16B)
  int wb = wv * 512;  // elems (1KB per wave per gload)
  auto stage = [&](int slot, int s) {
    int k0 = s * 32;
    u16* base = &lds[slot][0];
    gload_lds16(aSrc + k0, base + wb);                // A rows (all 128)
    gload_lds16(bSrc0 + k0, base + 4096 + wb);        // B rows 0..127
    gload_lds16(bSrc1 + k0, base + 8192 + wb);        // B rows 128..255
  };

  // ---- compute setup
  int lr = lane & 15;
  int quad = lane >> 4;                        // 0..3 = k-chunk
  int chunkOff = (quad ^ ((lr >> 1) & 3)) * 8; // swizzled read pos (elems)
  int wm = wv >> 2, wn = wv & 3;
  int wrr = wm * 64, wcc = wn * 64;

  int aOff[4], bOff[4];
#pragma unroll
  for (int m = 0; m < 4; ++m) aOff[m] = (wrr + m * 16 + lr) * 32 + chunkOff;
#pragma unroll
  for (int n = 0; n < 4; ++n) bOff[n] = 4096 + (wcc + n * 16 + lr) * 32 + chunkOff;

  f32x4 acc[4][4] = {};

  auto computeSub = [&](const u16* S) {
    bf16x8 af[4], bf[4];
#pragma unroll
    for (int m = 0; m < 4; ++m) af[m] = *(const bf16x8*)(S + aOff[m]);
#pragma unroll
    for (int n = 0; n < 4; ++n) bf[n] = *(const bf16x8*)(S + bOff[n]);
    __builtin_amdgcn_s_setprio(1);
#pragma unroll
    for (int m = 0; m < 4; ++m)
#pragma unroll
      for (int n = 0; n < 4; ++n)
        acc[m][n] = __builtin_amdgcn_mfma_f32_16x16x32_bf16(af[m], bf[n], acc[m][n], 0, 0, 0);
    __builtin_amdgcn_s_setprio(0);
  };

  // ---- pipelined ring: stage(s+2) in flight while computing s.
  // vmcnt = 3 loads/wave/stage * (#stages issued beyond s): 6 / 3 / 0.
  stage(0, 0);
  stage(1, 1);
#pragma unroll 1
  for (int s = 0; s < NSUB - 2; ++s) {
    stage((s + 2) % 3, s + 2);
    asm volatile("s_waitcnt vmcnt(6)" ::: "memory");  // sub-tile s landed
    __builtin_amdgcn_s_barrier();
    computeSub(&lds[s % 3][0]);
    __builtin_amdgcn_s_barrier();   // all waves done with slot before refill
  }
  asm volatile("s_waitcnt vmcnt(3)" ::: "memory");
  __builtin_amdgcn_s_barrier();
  computeSub(&lds[(NSUB - 2) % 3][0]);
  __builtin_amdgcn_s_barrier();
  asm volatile("s_waitcnt vmcnt(0)" ::: "memory");
  __builtin_amdgcn_s_barrier();
  computeSub(&lds[(NSUB - 1) % 3][0]);

  // ---- epilogue
  int r4 = quad * 4;
  const float* be = bias + (size_t)e * DH;
#pragma unroll
  for (int m = 0; m < 4; ++m) {
#pragma unroll
    for (int n = 0; n < 4; ++n) {
      int col = n0 + wcc + n * 16 + lr;
      float bvv = be[col];
#pragma unroll
      for (int j = 0; j < 4; ++j) {
        int gr = m0 + wrr + m * 16 + r4 + j;
        if (gr < cnt) {
          float v = acc[m][n][j] + bvv;
          if (GELU) v = gelu_tanh(v);
          outb[(size_t)(seg + gr) * DH + col] = f2bf(v);
        }
      }
    }
  }
}

// ---- combine: out[t] = p0*eo[q0] + p1*eo[q1]   (bias already in eo)
//      16B/lane loads (u16x8); one block = 2 tokens.
__global__ __launch_bounds__(256) void combine_kernel(
    const u16* __restrict__ eo, const float* __restrict__ tkp,
    const int* __restrict__ posof, float* __restrict__ out) {
  int gid = blockIdx.x * 256 + threadIdx.x;
  int t = gid >> 7;
  int n = (gid & 127) * 8;
  float p0 = tkp[2 * t], p1 = tkp[2 * t + 1];
  int q0 = posof[2 * t], q1 = posof[2 * t + 1];
  u16x8 a = *(const u16x8*)(eo + (size_t)q0 * DH + n);
  u16x8 b = *(const u16x8*)(eo + (size_t)q1 * DH + n);
  float4 o0, o1;
  o0.x = p0 * bf2f(a[0]) + p1 * bf2f(b[0]);
  o0.y = p0 * bf2f(a[1]) + p1 * bf2f(b[1]);
  o0.z = p0 * bf2f(a[2]) + p1 * bf2f(b[2]);
  o0.w = p0 * bf2f(a[3]) + p1 * bf2f(b[3]);
  o1.x = p0 * bf2f(a[4]) + p1 * bf2f(b[4]);
  o1.y = p0 * bf2f(a[5]) + p1 * bf2f(b[5]);
  o1.z = p0 * bf2f(a[6]) + p1 * bf2f(b[6]);
  o1.w = p0 * bf2f(a[7]) + p1 * bf2f(b[7]);
  *(float4*)(out + (size_t)t * DH + n) = o0;
  *(float4*)(out + (size_t)t * DH + n + 4) = o1;
}

extern "C" void kernel_launch(void* const* d_in, const int* in_sizes, int n_in,
                              void* d_out, int out_size, void* d_ws, size_t ws_size,
                              hipStream_t stream) {
  const float* x = (const float*)d_in[0];
  const float* w_router = (const float*)d_in[1];
  const float* w1 = (const float*)d_in[2];
  const float* b1 = (const float*)d_in[3];
  const float* w2 = (const float*)d_in[4];
  const float* b2 = (const float*)d_in[5];
  float* out = (float*)d_out;                 // combined [NT][DH]
  float* logits = out + (size_t)NT * DH;      // [NT][NE]

  char* ws = (char*)d_ws;
  size_t off = 0;
  auto alloc = [&](size_t bytes) -> void* {
    void* p = ws + off;
    off = (off + bytes + 255) & ~(size_t)255;
    return p;
  };
  int* ctrl = (int*)alloc(256);  // counts[8] | cur[8]
  int* counts = ctrl;
  int* cur = ctrl + 8;
  int* tkidx = (int*)alloc((size_t)NTK * 4);
  float* tkp = (float*)alloc((size_t)NTK * 4);
  int* rows = (int*)alloc((size_t)NTK * 4);
  int* posof = (int*)alloc((size_t)NTK * 4);
  float* pp = (float*)alloc((size_t)NTK * 4);
  u16* w1t = (u16*)alloc((size_t)NE * DH * DH * 2);
  u16* w2t = (u16*)alloc((size_t)NE * DH * DH * 2);
  u16* hbuf = (u16*)alloc((size_t)NTK * DH * 2);
  u16* eo = (u16*)alloc((size_t)NTK * DH * 2);  // aliased as xb (disjoint lifetime)
  u16* xb = eo;  // prep writes xb; gemm1 reads it; gemm2 then overwrites eo

  hipMemsetAsync(ctrl, 0, 256, stream);

  // fused transpose (4096 blocks) + router (256 blocks)
  prep_kernel<<<4352, 256, 0, stream>>>(w1, w2, x, w_router, w1t, w2t,
                                        logits, tkidx, tkp, counts, xb);
  scatter_kernel<<<NTK / 1024, 1024, 0, stream>>>(tkidx, tkp, counts, cur,
                                                  rows, posof, pp);
  // grid: x = expert (pins expert e to XCD e), y = tile q (n-fastest);
  // worst case one expert owns all NTK tokens: nm=128 -> q<512 <= 544.
  gemm_kernel<1><<<dim3(8, 544, 1), 512, 0, stream>>>(xb, w1t, b1, counts, rows, hbuf);
  gemm_kernel<0><<<dim3(8, 544, 1), 512, 0, stream>>>(hbuf, w2t, b2, counts, rows, eo);
  combine_kernel<<<NT * DH / 8 / 256, 256, 0, stream>>>(eo, tkp, posof, out);
}

// Round 14
// 179.563 us; speedup vs baseline: 1.0448x; 1.0448x over previous
//
#include <hip/hip_runtime.h>
#include <hip/hip_bf16.h>

#define DH 1024      // hidden dim
#define NE 8         // experts
#define NT 8192      // tokens (4*2048)
#define NTK 16384    // tokens * top-k
#define BM 128
#define BN 256
#define NSUB 32      // K sub-tiles of 32

typedef __bf16 bf16x8 __attribute__((ext_vector_type(8)));
typedef float f32x4 __attribute__((ext_vector_type(4)));
typedef unsigned short u16;
typedef u16 u16x8 __attribute__((ext_vector_type(8)));
typedef u16 u16x4 __attribute__((ext_vector_type(4)));

__device__ __forceinline__ u16 f2bf(float f) {
  union { float f; unsigned u; } v; v.f = f;
  return (u16)((v.u + 0x7fffu + ((v.u >> 16) & 1u)) >> 16);  // RNE
}
__device__ __forceinline__ float bf2f(u16 h) {
  union { unsigned u; float f; } v; v.u = ((unsigned)h) << 16;
  return v.f;
}
__device__ __forceinline__ float gelu_tanh(float v) {
  float y = 0.7978845608028654f * (v + 0.044715f * v * v * v);
  float t = 1.f - 2.f / (1.f + __expf(2.f * y));   // tanh(y)
  return 0.5f * v * (1.f + t);
}

// async global->LDS, 16B per lane; lane l lands at ldsbase + l*16B.
__device__ __forceinline__ void gload_lds16(const u16* g, u16* l) {
  __builtin_amdgcn_global_load_lds(
      (const __attribute__((address_space(1))) void*)g,
      (__attribute__((address_space(3))) void*)l, 16, 0, 0);
}

// ---- weight transpose + bf16 convert: w[e][d][n] (f32) -> wt[e][n][d] (bf16)
//      bf16-in-LDS (9.2KB tile -> high occupancy), u16x8 coalesced writes.
__global__ __launch_bounds__(256) void prep_transpose(
    const float* __restrict__ w1, const float* __restrict__ w2,
    u16* __restrict__ w1t, u16* __restrict__ w2t) {
  __shared__ u16 tile[64][72];   // [d][n], bf16, padded
  int z = blockIdx.z;  // 0..7 -> w1, 8..15 -> w2
  const float* src = (z < NE) ? (w1 + (size_t)z * DH * DH) : (w2 + (size_t)(z - NE) * DH * DH);
  u16* dst = (z < NE) ? (w1t + (size_t)z * DH * DH) : (w2t + (size_t)(z - NE) * DH * DH);
  int d0 = blockIdx.y * 64, n0 = blockIdx.x * 64;
  int tid = threadIdx.x;
  int r16 = tid >> 4;       // 0..15
  int c4 = (tid & 15) * 4;  // 0..60
#pragma unroll
  for (int it = 0; it < 4; ++it) {
    int rr = it * 16 + r16;
    float4 v = *(const float4*)&src[(size_t)(d0 + rr) * DH + n0 + c4];
    u16x4 o;
    o[0] = f2bf(v.x); o[1] = f2bf(v.y); o[2] = f2bf(v.z); o[3] = f2bf(v.w);
    *(u16x4*)&tile[rr][c4] = o;
  }
  __syncthreads();
  // write: thread covers n-row (tid>>2), d-chunk (tid&3)*16; 32B/thread,
  // 4 consecutive threads cover 128B contiguous of one n-row (coalesced).
  int n = tid >> 2;
  int dc = (tid & 3) * 16;
  u16x8 o0, o1;
#pragma unroll
  for (int j = 0; j < 8; ++j) o0[j] = tile[dc + j][n];
#pragma unroll
  for (int j = 0; j < 8; ++j) o1[j] = tile[dc + 8 + j][n];
  u16* drow = dst + (size_t)(n0 + n) * DH + d0 + dc;
  *(u16x8*)drow = o0;
  *(u16x8*)(drow + 8) = o1;
}

// ---- router (fused x->bf16 convert): 32 tokens/block (8 per wave).
__global__ __launch_bounds__(256) void router_kernel(
    const float* __restrict__ x, const float* __restrict__ wr,
    float* __restrict__ logits_out, int* __restrict__ tkidx,
    float* __restrict__ tkp, int* __restrict__ counts,
    u16* __restrict__ xb) {
  __shared__ float wsh[NE][DH + 8];
  __shared__ int hist[NE];
  int tid = threadIdx.x;
  for (int i = tid; i < DH * NE; i += 256) {
    int d = i >> 3, e = i & 7;
    wsh[e][d] = wr[i];
  }
  if (tid < NE) hist[tid] = 0;
  __syncthreads();

  int lane = tid & 63;
  int wv = tid >> 6;
  int t0 = blockIdx.x * 32 + wv * 8;
#pragma unroll 1
  for (int i = 0; i < 8; ++i) {
    int t = t0 + i;
    const float4* xp = (const float4*)(x + (size_t)t * DH);
    u16* xbrow = xb + (size_t)t * DH;
    float a[8] = {0.f, 0.f, 0.f, 0.f, 0.f, 0.f, 0.f, 0.f};
#pragma unroll
    for (int it = 0; it < 4; ++it) {
      float4 xv = xp[it * 64 + lane];
      int d0 = (it * 64 + lane) * 4;
      u16x4 c4;
      c4[0] = f2bf(xv.x); c4[1] = f2bf(xv.y); c4[2] = f2bf(xv.z); c4[3] = f2bf(xv.w);
      *(u16x4*)(xbrow + d0) = c4;
#pragma unroll
      for (int e = 0; e < 8; ++e) {
        float4 w4 = *(const float4*)&wsh[e][d0];
        a[e] += xv.x * w4.x + xv.y * w4.y + xv.z * w4.z + xv.w * w4.w;
      }
    }
#pragma unroll
    for (int off = 32; off; off >>= 1) {
#pragma unroll
      for (int e = 0; e < 8; ++e) a[e] += __shfl_xor(a[e], off, 64);
    }
    if (lane < 8) logits_out[(size_t)t * NE + lane] = a[lane];
    if (lane == 0) {
      float m1 = a[0]; int i1 = 0;
#pragma unroll
      for (int e = 1; e < 8; ++e) if (a[e] > m1) { m1 = a[e]; i1 = e; }
      float m2 = -3.4e38f; int i2 = 0;
#pragma unroll
      for (int e = 0; e < 8; ++e) if (e != i1 && a[e] > m2) { m2 = a[e]; i2 = e; }
      float den = 0.f;
#pragma unroll
      for (int e = 0; e < 8; ++e) den += expf(a[e] - m1);
      tkidx[2 * t] = i1; tkidx[2 * t + 1] = i2;
      tkp[2 * t] = 1.0f / den;
      tkp[2 * t + 1] = expf(m2 - m1) / den;
      atomicAdd(&hist[i1], 1);
      atomicAdd(&hist[i2], 1);
    }
  }
  __syncthreads();
  if (tid < NE) atomicAdd(&counts[tid], hist[tid]);
}

// ---- scatter: block-hierarchical ranks; 8 global atomics per block.
//      Computes the expert-offset prefix locally (no offsets kernel).
__global__ __launch_bounds__(1024) void scatter_kernel(
    const int* __restrict__ tkidx,
    const int* __restrict__ counts, int* __restrict__ cur,
    int* __restrict__ rows, int* __restrict__ posof) {
  __shared__ int h[NE];
  __shared__ int base[NE];
  __shared__ int offsL[NE];
  int tid = threadIdx.x;
  int gid = blockIdx.x * 1024 + tid;  // < NTK
  if (tid < NE) h[tid] = 0;
  if (tid == 0) {
    int s = 0;
    for (int e = 0; e < NE; ++e) { offsL[e] = s; s += counts[e]; }
  }
  __syncthreads();
  int e = tkidx[gid];
  int myrank = atomicAdd(&h[e], 1);
  __syncthreads();
  if (tid < NE) base[tid] = atomicAdd(&cur[tid], h[tid]);
  __syncthreads();
  int pos = offsL[e] + base[e] + myrank;
  rows[pos] = gid >> 1;
  posof[gid] = pos;
}

// ---- grouped GEMM (r12 champion, unchanged):
//      128x256 tile, ring of 3 BK=32 sub-tile buffers (72KB, 2 blk/CU),
//      counted vmcnt(6)/3/0 (T3+T4), chunk-XOR swizzle both-sides (T2,
//      0-conflict verified), setprio MFMA (T5). blockIdx.x = expert:
//      round-robin id%8 pins expert e's 2MB weights into XCD e's L2.
// GELU=1: A = xb gathered via rows[]; out = gelu(A@W + b)   -> hbuf
// GELU=0: A = hbuf direct;           out = A@W + b          -> eo
template <int GELU>
__global__ __launch_bounds__(512, 4) void gemm_kernel(
    const u16* __restrict__ A, const u16* __restrict__ W,
    const float* __restrict__ bias, const int* __restrict__ counts,
    const int* __restrict__ rows, u16* __restrict__ outb) {
  int e = blockIdx.x;               // expert == XCD (id % 8 round-robin)
  int q = blockIdx.y;               // tile index within expert, n-fastest
  int cnt = counts[e];
  int nm = (cnt + BM - 1) / BM;
  if (q >= nm * 4) return;          // block-uniform, before any barrier
  int m0 = (q >> 2) * BM;
  int n0 = (q & 3) * BN;
  int seg = 0;
  for (int i = 0; i < e; ++i) seg += counts[i];   // uniform prefix

  // ring slot: A[128][32] (8KB) at 0, B[256][32] (16KB) at elem 4096
  __shared__ __attribute__((aligned(16))) u16 lds[3][12288];

  int tid = threadIdx.x;
  int lane = tid & 63;
  int wv = tid >> 6;            // 0..7

  // ---- staging: thread covers row tid>>2, chunk tid&3 (16B chunks of 64B
  // rows). Global chunk pre-swizzled: stored pos = c ^ ((row>>1)&3); same
  // XOR applied to source (involution, rule #21). ((128+r)>>1)&3 ==
  // ((r>>1)&3), so one swizzled offset serves A and both B halves.
  int srow = tid >> 2;                               // 0..127
  int sc8 = ((tid & 3) ^ ((srow >> 1) & 3)) * 8;     // elems
  int gi = m0 + srow;
  int cl = gi < cnt ? gi : cnt - 1;
  int arow = GELU ? rows[seg + cl] : (seg + cl);
  const u16* aSrc = A + (size_t)arow * DH + sc8;
  const u16* bSrc0 = W + (size_t)e * DH * DH + (size_t)(n0 + srow) * DH + sc8;
  const u16* bSrc1 = bSrc0 + (size_t)128 * DH;

  // per-wave-uniform LDS bases (gload writes lane l at base + l*16B)
  int wb = wv * 512;  // elems (1KB per wave per gload)
  auto stage = [&](int slot, int s) {
    int k0 = s * 32;
    u16* base = &lds[slot][0];
    gload_lds16(aSrc + k0, base + wb);                // A rows (all 128)
    gload_lds16(bSrc0 + k0, base + 4096 + wb);        // B rows 0..127
    gload_lds16(bSrc1 + k0, base + 8192 + wb);        // B rows 128..255
  };

  // ---- compute setup
  int lr = lane & 15;
  int quad = lane >> 4;                        // 0..3 = k-chunk
  int chunkOff = (quad ^ ((lr >> 1) & 3)) * 8; // swizzled read pos (elems)
  int wm = wv >> 2, wn = wv & 3;
  int wrr = wm * 64, wcc = wn * 64;

  int aOff[4], bOff[4];
#pragma unroll
  for (int m = 0; m < 4; ++m) aOff[m] = (wrr + m * 16 + lr) * 32 + chunkOff;
#pragma unroll
  for (int n = 0; n < 4; ++n) bOff[n] = 4096 + (wcc + n * 16 + lr) * 32 + chunkOff;

  f32x4 acc[4][4] = {};

  auto computeSub = [&](const u16* S) {
    bf16x8 af[4], bf[4];
#pragma unroll
    for (int m = 0; m < 4; ++m) af[m] = *(const bf16x8*)(S + aOff[m]);
#pragma unroll
    for (int n = 0; n < 4; ++n) bf[n] = *(const bf16x8*)(S + bOff[n]);
    __builtin_amdgcn_s_setprio(1);
#pragma unroll
    for (int m = 0; m < 4; ++m)
#pragma unroll
      for (int n = 0; n < 4; ++n)
        acc[m][n] = __builtin_amdgcn_mfma_f32_16x16x32_bf16(af[m], bf[n], acc[m][n], 0, 0, 0);
    __builtin_amdgcn_s_setprio(0);
  };

  // ---- pipelined ring: stage(s+2) in flight while computing s.
  // vmcnt = 3 loads/wave/stage * (#stages issued beyond s): 6 / 3 / 0.
  stage(0, 0);
  stage(1, 1);
#pragma unroll 1
  for (int s = 0; s < NSUB - 2; ++s) {
    stage((s + 2) % 3, s + 2);
    asm volatile("s_waitcnt vmcnt(6)" ::: "memory");  // sub-tile s landed
    __builtin_amdgcn_s_barrier();
    computeSub(&lds[s % 3][0]);
    __builtin_amdgcn_s_barrier();   // all waves done with slot before refill
  }
  asm volatile("s_waitcnt vmcnt(3)" ::: "memory");
  __builtin_amdgcn_s_barrier();
  computeSub(&lds[(NSUB - 2) % 3][0]);
  __builtin_amdgcn_s_barrier();
  asm volatile("s_waitcnt vmcnt(0)" ::: "memory");
  __builtin_amdgcn_s_barrier();
  computeSub(&lds[(NSUB - 1) % 3][0]);

  // ---- epilogue
  int r4 = quad * 4;
  const float* be = bias + (size_t)e * DH;
#pragma unroll
  for (int m = 0; m < 4; ++m) {
#pragma unroll
    for (int n = 0; n < 4; ++n) {
      int col = n0 + wcc + n * 16 + lr;
      float bvv = be[col];
#pragma unroll
      for (int j = 0; j < 4; ++j) {
        int gr = m0 + wrr + m * 16 + r4 + j;
        if (gr < cnt) {
          float v = acc[m][n][j] + bvv;
          if (GELU) v = gelu_tanh(v);
          outb[(size_t)(seg + gr) * DH + col] = f2bf(v);
        }
      }
    }
  }
}

// ---- combine: out[t] = p0*eo[q0] + p1*eo[q1]   (bias already in eo)
//      16B/lane loads (u16x8); 128 threads per token.
__global__ __launch_bounds__(256) void combine_kernel(
    const u16* __restrict__ eo, const float* __restrict__ tkp,
    const int* __restrict__ posof, float* __restrict__ out) {
  int gid = blockIdx.x * 256 + threadIdx.x;
  int t = gid >> 7;
  int n = (gid & 127) * 8;
  float p0 = tkp[2 * t], p1 = tkp[2 * t + 1];
  int q0 = posof[2 * t], q1 = posof[2 * t + 1];
  u16x8 a = *(const u16x8*)(eo + (size_t)q0 * DH + n);
  u16x8 b = *(const u16x8*)(eo + (size_t)q1 * DH + n);
  float4 o0, o1;
  o0.x = p0 * bf2f(a[0]) + p1 * bf2f(b[0]);
  o0.y = p0 * bf2f(a[1]) + p1 * bf2f(b[1]);
  o0.z = p0 * bf2f(a[2]) + p1 * bf2f(b[2]);
  o0.w = p0 * bf2f(a[3]) + p1 * bf2f(b[3]);
  o1.x = p0 * bf2f(a[4]) + p1 * bf2f(b[4]);
  o1.y = p0 * bf2f(a[5]) + p1 * bf2f(b[5]);
  o1.z = p0 * bf2f(a[6]) + p1 * bf2f(b[6]);
  o1.w = p0 * bf2f(a[7]) + p1 * bf2f(b[7]);
  *(float4*)(out + (size_t)t * DH + n) = o0;
  *(float4*)(out + (size_t)t * DH + n + 4) = o1;
}

extern "C" void kernel_launch(void* const* d_in, const int* in_sizes, int n_in,
                              void* d_out, int out_size, void* d_ws, size_t ws_size,
                              hipStream_t stream) {
  const float* x = (const float*)d_in[0];
  const float* w_router = (const float*)d_in[1];
  const float* w1 = (const float*)d_in[2];
  const float* b1 = (const float*)d_in[3];
  const float* w2 = (const float*)d_in[4];
  const float* b2 = (const float*)d_in[5];
  float* out = (float*)d_out;                 // combined [NT][DH]
  float* logits = out + (size_t)NT * DH;      // [NT][NE]

  char* ws = (char*)d_ws;
  size_t off = 0;
  auto alloc = [&](size_t bytes) -> void* {
    void* p = ws + off;
    off = (off + bytes + 255) & ~(size_t)255;
    return p;
  };
  int* ctrl = (int*)alloc(256);  // counts[8] | cur[8]
  int* counts = ctrl;
  int* cur = ctrl + 8;
  int* tkidx = (int*)alloc((size_t)NTK * 4);
  float* tkp = (float*)alloc((size_t)NTK * 4);
  int* rows = (int*)alloc((size_t)NTK * 4);
  int* posof = (int*)alloc((size_t)NTK * 4);
  u16* w1t = (u16*)alloc((size_t)NE * DH * DH * 2);
  u16* w2t = (u16*)alloc((size_t)NE * DH * DH * 2);
  u16* hbuf = (u16*)alloc((size_t)NTK * DH * 2);
  u16* eo = (u16*)alloc((size_t)NTK * DH * 2);  // aliased as xb (disjoint lifetime)
  u16* xb = eo;  // router writes xb; gemm1 reads it; gemm2 then overwrites eo

  hipMemsetAsync(ctrl, 0, 256, stream);

  prep_transpose<<<dim3(16, 16, 16), 256, 0, stream>>>(w1, w2, w1t, w2t);
  router_kernel<<<NT / 32, 256, 0, stream>>>(x, w_router, logits, tkidx, tkp, counts, xb);
  scatter_kernel<<<NTK / 1024, 1024, 0, stream>>>(tkidx, counts, cur, rows, posof);
  // grid: x = expert (pins expert e to XCD e), y = tile q (n-fastest);
  // worst case one expert owns all NTK tokens: nm=128 -> q<512 <= 544.
  gemm_kernel<1><<<dim3(8, 544, 1), 512, 0, stream>>>(xb, w1t, b1, counts, rows, hbuf);
  gemm_kernel<0><<<dim3(8, 544, 1), 512, 0, stream>>>(hbuf, w2t, b2, counts, rows, eo);
  combine_kernel<<<NT * DH / 8 / 256, 256, 0, stream>>>(eo, tkp, posof, out);
}